// Round 2
// baseline (120.996 us; speedup 1.0000x reference)
//
#include <hip/hip_runtime.h>

#define T_SEQ 50
#define BATCH 8192
#define INPUT 33
#define HID   256
#define BTILE 32
#define NTH   512

typedef __attribute__((ext_vector_type(8))) short short8;
typedef __attribute__((ext_vector_type(4))) short short4v;
typedef __attribute__((ext_vector_type(4))) float float4v;

// LDS layout (units: shorts). Rows padded +8 shorts (16B) -> 2-way bank aliasing only.
#define WH_STRIDE 264                         // 256 + 8 pad
#define H_OFF     (HID * WH_STRIDE)           // 67584
#define X_STRIDE  72                          // 64 + 8 pad
#define X_OFF     (H_OFF + BTILE * WH_STRIDE) // 76032
#define LDS_SHORTS (X_OFF + BTILE * X_STRIDE) // 78336 shorts = 156672 B  (<= 160 KiB)

__device__ __forceinline__ short f2bf(float v) {   // RNE f32 -> bf16 bits
  unsigned u = __builtin_bit_cast(unsigned, v);
  u = (u + 0x7FFFu + ((u >> 16) & 1u)) >> 16;
  return (short)u;
}

__global__ __launch_bounds__(NTH, 2)
void ctrnn_kernel(const float* __restrict__ x, const int* __restrict__ sub_id,
                  const float* __restrict__ gates, const float* __restrict__ W_in,
                  const float* __restrict__ b_in, const float* __restrict__ W_h,
                  const float* __restrict__ b_h, float* __restrict__ out)
{
  extern __shared__ short lds[];
  const int tid  = threadIdx.x;
  const int lane = tid & 63;
  const int wave = tid >> 6;
  const int colA = lane & 15;   // MFMA row/col-within-tile index
  const int kq   = lane >> 4;   // 0..3 k-quadrant / C-row group
  const int c0   = wave * 32;   // this wave's output-column base (8 waves x 32 = 256)
  const int brow0 = blockIdx.x * BTILE;

  const int sid = sub_id[0];
  const float* grow = gates + sid * HID;

  // ---- W_h' = diag(g) * W_h  ->  LDS bf16, padded rows (one-time) ----
  #pragma unroll 4
  for (int it = 0; it < 32; ++it) {
    int e4 = (it * NTH + tid) * 4;      // 65536 elems total
    int row = e4 >> 8;
    int col = e4 & 255;
    float4v w = *(const float4v*)(W_h + e4);
    float g = grow[row];
    short4v s;
    s[0] = f2bf(g * w[0]); s[1] = f2bf(g * w[1]);
    s[2] = f2bf(g * w[2]); s[3] = f2bf(g * w[3]);
    *(short4v*)(lds + row * WH_STRIDE + col) = s;
  }

  // ---- zero h-state and x staging regions (h0 = 0; x pad cols stay 0) ----
  {
    int* ldsi = (int*)(lds + H_OFF);
    const int nInt = (BTILE * WH_STRIDE + BTILE * X_STRIDE) / 2;
    for (int i = tid; i < nInt; i += NTH) ldsi[i] = 0;
  }
  // RACE FIX: the zero-fill above and the x0 staging below touch the same
  // LDS words from DIFFERENT threads. Order must be zero -> stage.
  __syncthreads();

  // ---- persistent W_in B-fragments (regs) + folded bias ----
  short8 win[2][2];
  float  bc[2];
  #pragma unroll
  for (int n = 0; n < 2; ++n) {
    int wcol = c0 + n * 16 + colA;
    #pragma unroll
    for (int kb = 0; kb < 2; ++kb) {
      short8 f;
      #pragma unroll
      for (int j = 0; j < 8; ++j) {
        int kk = kb * 32 + kq * 8 + j;
        float v = (kk < INPUT) ? W_in[wcol * INPUT + kk] : 0.0f;
        f[j] = f2bf(v);
      }
      win[n][kb] = f;
    }
    bc[n] = b_in[wcol] + grow[wcol] * b_h[wcol];
  }

  // ---- stage x_0 ----
  {
    const float* xt = x + (size_t)brow0 * INPUT;
    for (int e = tid; e < BTILE * INPUT; e += NTH) {
      int r = e / INPUT, c = e - r * INPUT;
      lds[X_OFF + r * X_STRIDE + c] = f2bf(xt[e]);
    }
  }

  // x-prefetch loop invariants (each thread covers elems tid, tid+512, tid+1024)
  const int e0 = tid, e1 = tid + NTH, e2 = tid + 2 * NTH;
  const int r0 = e0 / INPUT, c0x = e0 - r0 * INPUT;
  const int r1 = e1 / INPUT, c1x = e1 - r1 * INPUT;
  const int r2 = e2 / INPUT, c2x = e2 - r2 * INPUT;
  const bool p2 = (e2 < BTILE * INPUT);

  // persistent f32 h state at MFMA C-layout: col = c0+n*16+colA, row = m*16+kq*4+i
  float4v hreg[2][2];
  #pragma unroll
  for (int m = 0; m < 2; ++m)
    #pragma unroll
    for (int n = 0; n < 2; ++n)
      #pragma unroll
      for (int i = 0; i < 4; ++i) hreg[m][n][i] = 0.0f;

  float* outp0 = out + (size_t)(brow0 + kq * 4) * HID + c0 + colA;  // m = 0 base
  float* outp1 = outp0 + 16 * HID;                                  // m = 1 base
  const int outstep = BATCH * HID;
  const float* xpf = x + (size_t)brow0 * INPUT;
  const int xstep = BATCH * INPUT;

  __syncthreads();

  #pragma unroll 1
  for (int t = 0; t < T_SEQ; ++t) {
    // prefetch x_{t+1} into regs (consumed after the mid barrier)
    float xp0 = 0.f, xp1 = 0.f, xp2 = 0.f;
    if (t + 1 < T_SEQ) {
      const float* xt1 = xpf + (size_t)(t + 1) * xstep;
      xp0 = xt1[e0]; xp1 = xt1[e1];
      if (p2) xp2 = xt1[e2];
    }

    // seed accumulators with h + bc  ->  h_new = relu(0.5 * acc_final)
    float4v acc[2][2];
    #pragma unroll
    for (int m = 0; m < 2; ++m)
      #pragma unroll
      for (int n = 0; n < 2; ++n)
        #pragma unroll
        for (int i = 0; i < 4; ++i)
          acc[m][n][i] = hreg[m][n][i] + bc[n];

    const short* hb = lds + H_OFF;
    const short* wb = lds;
    const short* xb = lds + X_OFF;

    // recurrent part: K = 256 over W_h' (LDS) x h_bf16 (LDS)
    #pragma unroll
    for (int ks = 0; ks < 8; ++ks) {
      int k = ks * 32 + kq * 8;
      short8 a0 = *(const short8*)(hb + colA * WH_STRIDE + k);
      short8 a1 = *(const short8*)(hb + (16 + colA) * WH_STRIDE + k);
      short8 b0 = *(const short8*)(wb + (c0 + colA) * WH_STRIDE + k);
      short8 b1 = *(const short8*)(wb + (c0 + 16 + colA) * WH_STRIDE + k);
      acc[0][0] = __builtin_amdgcn_mfma_f32_16x16x32_bf16(a0, b0, acc[0][0], 0, 0, 0);
      acc[0][1] = __builtin_amdgcn_mfma_f32_16x16x32_bf16(a0, b1, acc[0][1], 0, 0, 0);
      acc[1][0] = __builtin_amdgcn_mfma_f32_16x16x32_bf16(a1, b0, acc[1][0], 0, 0, 0);
      acc[1][1] = __builtin_amdgcn_mfma_f32_16x16x32_bf16(a1, b1, acc[1][1], 0, 0, 0);
    }
    // input part: K = 64 (x padded with zeros), W_in fragments from registers
    #pragma unroll
    for (int kb = 0; kb < 2; ++kb) {
      int k = kb * 32 + kq * 8;
      short8 a0 = *(const short8*)(xb + colA * X_STRIDE + k);
      short8 a1 = *(const short8*)(xb + (16 + colA) * X_STRIDE + k);
      acc[0][0] = __builtin_amdgcn_mfma_f32_16x16x32_bf16(a0, win[0][kb], acc[0][0], 0, 0, 0);
      acc[0][1] = __builtin_amdgcn_mfma_f32_16x16x32_bf16(a0, win[1][kb], acc[0][1], 0, 0, 0);
      acc[1][0] = __builtin_amdgcn_mfma_f32_16x16x32_bf16(a1, win[0][kb], acc[1][0], 0, 0, 0);
      acc[1][1] = __builtin_amdgcn_mfma_f32_16x16x32_bf16(a1, win[1][kb], acc[1][1], 0, 0, 0);
    }

    // h_new = relu(0.5 * acc); keep f32 master in regs; stream f32 to HBM
    #pragma unroll
    for (int m = 0; m < 2; ++m)
      #pragma unroll
      for (int n = 0; n < 2; ++n)
        #pragma unroll
        for (int i = 0; i < 4; ++i) {
          float hn = fmaxf(0.5f * acc[m][n][i], 0.0f);
          hreg[m][n][i] = hn;
          (m == 0 ? outp0 : outp1)[i * HID + n * 16] = hn;
        }

    __syncthreads();   // all waves done reading h_lds/x_lds for step t

    // restage h_new as bf16 for next step's A operand
    #pragma unroll
    for (int m = 0; m < 2; ++m)
      #pragma unroll
      for (int n = 0; n < 2; ++n)
        #pragma unroll
        for (int i = 0; i < 4; ++i) {
          int row = m * 16 + kq * 4 + i;
          int col = c0 + n * 16 + colA;
          lds[H_OFF + row * WH_STRIDE + col] = f2bf(hreg[m][n][i]);
        }
    // write prefetched x_{t+1}
    if (t + 1 < T_SEQ) {
      lds[X_OFF + r0 * X_STRIDE + c0x] = f2bf(xp0);
      lds[X_OFF + r1 * X_STRIDE + c1x] = f2bf(xp1);
      if (p2) lds[X_OFF + r2 * X_STRIDE + c2x] = f2bf(xp2);
    }
    __syncthreads();   // h_lds/x_lds ready for step t+1

    outp0 += outstep; outp1 += outstep;
  }

  // h_last = h after step T-1
  {
    float* hp = out + (size_t)T_SEQ * BATCH * HID + (size_t)(brow0 + kq * 4) * HID + c0 + colA;
    #pragma unroll
    for (int m = 0; m < 2; ++m)
      #pragma unroll
      for (int n = 0; n < 2; ++n)
        #pragma unroll
        for (int i = 0; i < 4; ++i)
          hp[(m * 16 + i) * HID + n * 16] = hreg[m][n][i];
  }
}

extern "C" void kernel_launch(void* const* d_in, const int* in_sizes, int n_in,
                              void* d_out, int out_size, void* d_ws, size_t ws_size,
                              hipStream_t stream) {
  const float* x    = (const float*)d_in[0];
  const int*   sid  = (const int*)  d_in[1];
  const float* gts  = (const float*)d_in[2];
  const float* W_in = (const float*)d_in[3];
  const float* b_in = (const float*)d_in[4];
  const float* W_h  = (const float*)d_in[5];
  const float* b_h  = (const float*)d_in[6];
  float* out = (float*)d_out;

  const size_t ldsB = (size_t)LDS_SHORTS * sizeof(short);  // 156672 B
  (void)hipFuncSetAttribute(reinterpret_cast<const void*>(ctrnn_kernel),
                            hipFuncAttributeMaxDynamicSharedMemorySize, (int)ldsB);
  ctrnn_kernel<<<BATCH / BTILE, NTH, ldsB, stream>>>(x, sid, gts, W_in, b_in, W_h, b_h, out);
}